// Round 23
// baseline (133.405 us; speedup 1.0000x reference)
//
#include <hip/hip_runtime.h>
#include <math.h>

typedef __bf16 bf16;
typedef bf16 bf16x8 __attribute__((ext_vector_type(8)));
typedef bf16 bf16x4 __attribute__((ext_vector_type(4)));
typedef float f32x4 __attribute__((ext_vector_type(4)));
typedef unsigned long long u64;

constexpr int kB = 8, kC = 512, kC4 = 128, kN = 2048;

#define MFMA16(a, b, c) __builtin_amdgcn_mfma_f32_16x16x32_bf16(a, b, c, 0, 0, 0)
#define MFMA8(a, b, c) \
  __builtin_amdgcn_mfma_f32_16x16x32_fp8_fp8(a, b, c, 0, 0, 0)

__device__ __forceinline__ unsigned pack4_fp8(float a, float b, float c,
                                              float d) {
  unsigned v = 0;
  v = __builtin_amdgcn_cvt_pk_fp8_f32(a, b, v, false);
  v = __builtin_amdgcn_cvt_pk_fp8_f32(c, d, v, true);
  return v;
}

// barrier with LDS drain only (no vmcnt drain)
__device__ __forceinline__ void barrier_lds() {
  asm volatile("s_waitcnt lgkmcnt(0)\n\ts_barrier" ::: "memory");
}

// ---------------------------------------------------------------- prep
__global__ __launch_bounds__(256) void k_prep(
    const int* __restrict__ mask, const float* __restrict__ wqk,
    const float* __restrict__ wv, const float* __restrict__ wt,
    const float* __restrict__ gamma, const float* __restrict__ rvar,
    float* __restrict__ cnt, bf16* __restrict__ wqk_bf,
    bf16* __restrict__ wv_bf, bf16* __restrict__ wt_bf,
    float* __restrict__ invg, float* __restrict__ Ssum) {
  const int t = threadIdx.x;
  if (blockIdx.x < 8) {
    const int b = blockIdx.x;
    int s = 0;
    for (int i = t; i < kN; i += 256) s += mask[b * kN + i];
    __shared__ int red[256];
    red[t] = s;
    __syncthreads();
    for (int off = 128; off > 0; off >>= 1) {
      if (t < off) red[t] += red[t + off];
      __syncthreads();
    }
    if (t == 0) cnt[b] = (float)red[0];
    return;
  }
  const int total = 65536 + 262144 + 262144 + 512 + 16384;
  for (int i = (blockIdx.x - 8) * 256 + t; i < total; i += 128 * 256) {
    if (i < 65536) {
      wqk_bf[i] = (bf16)wqk[i];
    } else if (i < 327680) {
      wv_bf[i - 65536] = (bf16)wv[i - 65536];
    } else if (i < 589824) {
      wt_bf[i - 327680] = (bf16)wt[i - 327680];
    } else if (i < 590336) {
      const int j = i - 589824;
      invg[j] = gamma[j] * rsqrtf(rvar[j] + 1e-5f);
    } else {
      Ssum[i - 590336] = 0.0f;
    }
  }
}

// ---------------- transpose+convert both inputs: [C][N] f32 -> [N][C] bf16
__global__ __launch_bounds__(256) void k_tr2(const float* __restrict__ Q,
                                             const float* __restrict__ X,
                                             bf16* __restrict__ XTq,
                                             bf16* __restrict__ XTx) {
  __shared__ float tile[32][69];
  const int z = blockIdx.z, b = z & 7;
  const float* Xs = (z < 8) ? Q : X;
  bf16* XT = (z < 8) ? XTq : XTx;
  const int c0 = blockIdx.y * 32, n0 = blockIdx.x * 64;
  const int t = threadIdx.x;
  const int cc = t >> 4, n4 = (t & 15) * 4;
#pragma unroll
  for (int p = 0; p < 2; p++) {
    const int c = p * 16 + cc;
    const f32x4 v =
        *(const f32x4*)&Xs[((size_t)(b * kC + c0 + c)) * kN + n0 + n4];
    tile[c][n4 + 0] = v[0];
    tile[c][n4 + 1] = v[1];
    tile[c][n4 + 2] = v[2];
    tile[c][n4 + 3] = v[3];
  }
  __syncthreads();
  const int n = t >> 2, c8 = (t & 3) * 8;
  bf16x8 o;
#pragma unroll
  for (int j = 0; j < 8; j++) o[j] = (bf16)tile[c8 + j][n];
  *(bf16x8*)&XT[((size_t)(b * kN + n0 + n)) * kC + c0 + c8] = o;
}

// -------- q/k projections (staged GEMM): OT8[b][n][128] fp8 = (wqk @ src)^T
__global__ __launch_bounds__(256, 2) void k_projQK(
    const bf16* __restrict__ XTq, const bf16* __restrict__ XTx,
    const bf16* __restrict__ W, unsigned char* __restrict__ qT8,
    unsigned char* __restrict__ kT8) {
  __shared__ __align__(16) bf16 As[2][128][32];
  __shared__ __align__(16) bf16 Bs[2][128][32];
  const int nb = blockIdx.x, b = blockIdx.y, src = blockIdx.z;
  const bf16* XT = src ? XTx : XTq;
  unsigned char* OT8 = src ? kT8 : qT8;
  const int n0 = nb * 128;
  const int t_ = threadIdx.x, w = t_ >> 6, l = t_ & 63, lo4 = l & 15, g = l >> 4;
  const int mh = w >> 1, ch = w & 1;
  const int srow = w * 16 + (l >> 2), sch = l & 3;
  const int spos = sch ^ ((l >> 3) & 3);
  const int rpos = g ^ ((lo4 >> 1) & 3);
  const bf16* gA0 = &XT[((size_t)(b * kN + n0 + srow)) * kC + sch * 8];
  const bf16* gA1 = gA0 + (size_t)64 * kC;
  const bf16* gB0 = &W[(size_t)srow * kC + sch * 8];
  const bf16* gB1 = gB0 + (size_t)64 * kC;
  f32x4 acc[4][4] = {};
  bf16x8 ra0, ra1, rb0, rb1;
  ra0 = *(const bf16x8*)&gA0[0];
  ra1 = *(const bf16x8*)&gA1[0];
  rb0 = *(const bf16x8*)&gB0[0];
  rb1 = *(const bf16x8*)&gB1[0];
  *(bf16x8*)&As[0][srow][spos * 8] = ra0;
  *(bf16x8*)&As[0][srow + 64][spos * 8] = ra1;
  *(bf16x8*)&Bs[0][srow][spos * 8] = rb0;
  *(bf16x8*)&Bs[0][srow + 64][spos * 8] = rb1;
  __syncthreads();
  for (int tt = 0; tt < 16; tt++) {
    const int buf = tt & 1;
    if (tt < 15) {
      const int k0 = (tt + 1) * 32;
      ra0 = *(const bf16x8*)&gA0[k0];
      ra1 = *(const bf16x8*)&gA1[k0];
      rb0 = *(const bf16x8*)&gB0[k0];
      rb1 = *(const bf16x8*)&gB1[k0];
    }
    bf16x8 af[4], bfr[4];
#pragma unroll
    for (int nf = 0; nf < 4; nf++)
      af[nf] = *(const bf16x8*)&As[buf][mh * 64 + nf * 16 + lo4][rpos * 8];
#pragma unroll
    for (int cf = 0; cf < 4; cf++)
      bfr[cf] = *(const bf16x8*)&Bs[buf][ch * 64 + cf * 16 + lo4][rpos * 8];
#pragma unroll
    for (int nf = 0; nf < 4; nf++)
#pragma unroll
      for (int cf = 0; cf < 4; cf++)
        acc[nf][cf] = MFMA16(af[nf], bfr[cf], acc[nf][cf]);
    if (tt < 15) {
      *(bf16x8*)&As[buf ^ 1][srow][spos * 8] = ra0;
      *(bf16x8*)&As[buf ^ 1][srow + 64][spos * 8] = ra1;
      *(bf16x8*)&Bs[buf ^ 1][srow][spos * 8] = rb0;
      *(bf16x8*)&Bs[buf ^ 1][srow + 64][spos * 8] = rb1;
    }
    __syncthreads();
  }
  // epilogue: per-wave LDS transpose -> fp8 pack -> OT8[n][d]
  bf16* bncw = ((bf16*)As) + w * 16 * 72;
#pragma unroll
  for (int nf = 0; nf < 4; nf++) {
    const int nbase = n0 + mh * 64 + nf * 16;
#pragma unroll
    for (int cf = 0; cf < 4; cf++)
#pragma unroll
      for (int r = 0; r < 4; r++)
        bncw[(4 * g + r) * 72 + cf * 16 + lo4] = (bf16)acc[nf][cf][r];
    const int rr = l >> 2, seg = (l & 3) * 16;
    const bf16x8 v0 = *(const bf16x8*)&bncw[rr * 72 + seg];
    const bf16x8 v1 = *(const bf16x8*)&bncw[rr * 72 + seg + 8];
    int4 o;
    o.x = (int)pack4_fp8((float)v0[0], (float)v0[1], (float)v0[2],
                         (float)v0[3]);
    o.y = (int)pack4_fp8((float)v0[4], (float)v0[5], (float)v0[6],
                         (float)v0[7]);
    o.z = (int)pack4_fp8((float)v1[0], (float)v1[1], (float)v1[2],
                         (float)v1[3]);
    o.w = (int)pack4_fp8((float)v1[4], (float)v1[5], (float)v1[6],
                         (float)v1[7]);
    *(int4*)&OT8[((size_t)(b * kN + nbase + rr)) * kC4 + ch * 64 + seg] = o;
  }
}

// ---------------- pass 1 (fp8 energy): UT8[m][n] = exp-factor; partial S[n]
__global__ __launch_bounds__(256) void k_sum(
    const unsigned char* __restrict__ qT8, const unsigned char* __restrict__ kT8,
    const int* __restrict__ mask, const float* __restrict__ cnt,
    unsigned char* __restrict__ UT8, float* __restrict__ Ssum) {
  __shared__ __align__(16) unsigned char kts[2][64][128];
  __shared__ __align__(16) unsigned Ubuf[64][16];
  __shared__ int mss[2][64];
  const int blk = blockIdx.x;
  const int b = blk & 7, nb = (blk >> 3) & 31, mh2 = blk >> 8;
  const int m00 = mh2 * 1024;
  const int t_ = threadIdx.x, w = t_ >> 6, l = t_ & 63, lo4 = l & 15, g = l >> 4;
  const float invd = 1.0f / (cnt[b] + 1e-9f);
  const int n0 = nb * 64;
  u64 aq[4];
#pragma unroll
  for (int ks = 0; ks < 4; ks++)
    aq[ks] = *(const u64*)&qT8[((size_t)(b * kN + n0 + w * 16 + lo4)) * kC4 +
                               ks * 32 + g * 8];
  const int nq = n0 + w * 16 + g * 4;
  const int4 mi = *(const int4*)&mask[b * kN + nq];
  const int mn4[4] = {mi.x, mi.y, mi.z, mi.w};
  float rs4[4] = {0.0f, 0.0f, 0.0f, 0.0f};
  const int srow = t_ >> 2, sq = t_ & 3;
  const int swk = srow & 15;
  u64 rg[4];
#pragma unroll
  for (int j = 0; j < 4; j++)
    rg[j] = *(const u64*)&kT8[((size_t)(b * kN + m00 + srow)) * kC4 + sq * 32 +
                              j * 8];
#pragma unroll
  for (int j = 0; j < 4; j++)
    *(u64*)&kts[0][srow][((sq * 4 + j) ^ swk) * 8] = rg[j];
  if (t_ < 16)
    *(int4*)&mss[0][t_ * 4] = *(const int4*)&mask[b * kN + m00 + t_ * 4];
  __syncthreads();
  for (int tt = 0; tt < 16; tt++) {
    const int buf = tt & 1;
    if (tt < 15) {
      const int m0 = m00 + (tt + 1) * 64;
#pragma unroll
      for (int j = 0; j < 4; j++)
        rg[j] = *(const u64*)&kT8[((size_t)(b * kN + m0 + srow)) * kC4 +
                                  sq * 32 + j * 8];
    }
#pragma unroll
    for (int mf = 0; mf < 4; mf++) {
      f32x4 e = {};
#pragma unroll
      for (int ks = 0; ks < 4; ks++) {
        const long bk =
            *(const long*)&kts[buf][mf * 16 + lo4][((ks * 4 + g) ^ lo4) * 8];
        e = MFMA8((long)aq[ks], bk, e);
      }
      const int mmv = mss[buf][mf * 16 + lo4];
      float u[4];
#pragma unroll
      for (int r = 0; r < 4; r++) {
        u[r] = mmv ? (mn4[r] ? __expf(e[r] * invd) : 1.0f) : 0.0f;
        rs4[r] += u[r];
      }
      Ubuf[mf * 16 + lo4][(w * 4 + g) ^ lo4] =
          pack4_fp8(u[0], u[1], u[2], u[3]);
    }
    __syncthreads();
    if (tt < 15) {
#pragma unroll
      for (int j = 0; j < 4; j++)
        *(u64*)&kts[buf ^ 1][srow][((sq * 4 + j) ^ swk) * 8] = rg[j];
      if (t_ < 16)
        *(int4*)&mss[buf ^ 1][t_ * 4] =
            *(const int4*)&mask[b * kN + m00 + (tt + 1) * 64 + t_ * 4];
    }
    {
      const int row = t_ >> 2, q = t_ & 3;
      int4 pkt;
      pkt.x = (int)Ubuf[row][(q * 4 + 0) ^ (row & 15)];
      pkt.y = (int)Ubuf[row][(q * 4 + 1) ^ (row & 15)];
      pkt.z = (int)Ubuf[row][(q * 4 + 2) ^ (row & 15)];
      pkt.w = (int)Ubuf[row][(q * 4 + 3) ^ (row & 15)];
      *(int4*)&UT8[((size_t)(b * kN + m00 + tt * 64 + row)) * kN + n0 +
                   q * 16] = pkt;
    }
    __syncthreads();
  }
#pragma unroll
  for (int r = 0; r < 4; r++) {
#pragma unroll
    for (int off = 1; off < 16; off <<= 1) rs4[r] += __shfl_xor(rs4[r], off);
  }
  if (lo4 == 0) {
#pragma unroll
    for (int r = 0; r < 4; r++) atomicAdd(&Ssum[b * kN + nq + r], rs4[r]);
  }
}

// -------- value projection fused with 256/Ssum scaling -> xv8 fp8 tiled
__global__ __launch_bounds__(256, 2) void k_projV(
    const bf16* __restrict__ XTx, const bf16* __restrict__ Wv,
    const float* __restrict__ bv, const float* __restrict__ Ssum,
    unsigned char* __restrict__ xv8) {
  __shared__ __align__(16) bf16 As[2][128][32];
  __shared__ __align__(16) bf16 Bs[2][128][32];
  const int blk = blockIdx.x;  // 512 = 8b x (16nb x 4cb)
  const int b = blk & 7, tile = blk >> 3;
  const int cb = tile & 3, nb = tile >> 2;
  const int n0 = nb * 128, c0 = cb * 128;
  const int t_ = threadIdx.x, w = t_ >> 6, l = t_ & 63, lo4 = l & 15, g = l >> 4;
  const int mh = w >> 1, ch = w & 1;
  const int srow = w * 16 + (l >> 2), sch = l & 3;
  const int spos = sch ^ ((l >> 3) & 3);
  const int rpos = g ^ ((lo4 >> 1) & 3);
  const bf16* gA0 = &XTx[((size_t)(b * kN + n0 + srow)) * kC + sch * 8];
  const bf16* gA1 = gA0 + (size_t)64 * kC;
  const bf16* gB0 = &Wv[(size_t)(c0 + srow) * kC + sch * 8];
  const bf16* gB1 = gB0 + (size_t)64 * kC;
  f32x4 acc[4][4] = {};
  bf16x8 ra0, ra1, rb0, rb1;
  ra0 = *(const bf16x8*)&gA0[0];
  ra1 = *(const bf16x8*)&gA1[0];
  rb0 = *(const bf16x8*)&gB0[0];
  rb1 = *(const bf16x8*)&gB1[0];
  *(bf16x8*)&As[0][srow][spos * 8] = ra0;
  *(bf16x8*)&As[0][srow + 64][spos * 8] = ra1;
  *(bf16x8*)&Bs[0][srow][spos * 8] = rb0;
  *(bf16x8*)&Bs[0][srow + 64][spos * 8] = rb1;
  __syncthreads();
  for (int tt = 0; tt < 16; tt++) {
    const int buf = tt & 1;
    if (tt < 15) {
      const int k0 = (tt + 1) * 32;
      ra0 = *(const bf16x8*)&gA0[k0];
      ra1 = *(const bf16x8*)&gA1[k0];
      rb0 = *(const bf16x8*)&gB0[k0];
      rb1 = *(const bf16x8*)&gB1[k0];
    }
    bf16x8 af[4], bfr[4];
#pragma unroll
    for (int nf = 0; nf < 4; nf++)
      af[nf] = *(const bf16x8*)&As[buf][mh * 64 + nf * 16 + lo4][rpos * 8];
#pragma unroll
    for (int cf = 0; cf < 4; cf++)
      bfr[cf] = *(const bf16x8*)&Bs[buf][ch * 64 + cf * 16 + lo4][rpos * 8];
#pragma unroll
    for (int nf = 0; nf < 4; nf++)
#pragma unroll
      for (int cf = 0; cf < 4; cf++)
        acc[nf][cf] = MFMA16(af[nf], bfr[cf], acc[nf][cf]);
    if (tt < 15) {
      *(bf16x8*)&As[buf ^ 1][srow][spos * 8] = ra0;
      *(bf16x8*)&As[buf ^ 1][srow + 64][spos * 8] = ra1;
      *(bf16x8*)&Bs[buf ^ 1][srow][spos * 8] = rb0;
      *(bf16x8*)&Bs[buf ^ 1][srow + 64][spos * 8] = rb1;
    }
    __syncthreads();
  }
  // epilogue: (acc + bias) * 256/Ssum[n] -> fp8, tiled layout
#pragma unroll
  for (int nf = 0; nf < 4; nf++) {
    const int nbase = n0 + mh * 64 + nf * 16 + g * 4;
    const f32x4 ssv = *(const f32x4*)&Ssum[b * kN + nbase];
    f32x4 s;
#pragma unroll
    for (int r = 0; r < 4; r++) s[r] = 256.0f / ssv[r];
#pragma unroll
    for (int cf = 0; cf < 4; cf++) {
      const int c = c0 + ch * 64 + cf * 16 + lo4;
      const float bvv = bv[c];
      const unsigned o = pack4_fp8((acc[nf][cf][0] + bvv) * s[0],
                                   (acc[nf][cf][1] + bvv) * s[1],
                                   (acc[nf][cf][2] + bvv) * s[2],
                                   (acc[nf][cf][3] + bvv) * s[3]);
      *(unsigned*)&xv8[(((size_t)b * 32 + (nbase >> 6)) * kC + c) * 64 +
                       (nbase & 63)] = o;
    }
  }
}

// -------- pass 2 (fp8, BK=128): x_r = 2^-8 * sum_n UT8[m][n]*xv8[c][n]
// SAME 128x128 tile / swizzle as r19, but 512 threads (8 waves = 2mh x 4ch,
// each 64m x 32c) -> 4 waves/SIMD at 2 blocks/CU.
__global__ __launch_bounds__(512, 4) void k_attn2(
    const unsigned char* __restrict__ UT8,
    const unsigned char* __restrict__ xv8, const float* __restrict__ x,
    bf16* __restrict__ hT) {
  __shared__ __align__(16) unsigned char As[2][128][128];
  __shared__ __align__(16) unsigned char Bs[2][128][128];
  const int blk = blockIdx.x;  // 512 = 8b x (16mb x 4cb)
  const int b = blk & 7, tile = blk >> 3;
  const int cb = tile & 3, mb = tile >> 2;
  const int m0 = mb * 128, c0 = cb * 128;
  const int t_ = threadIdx.x, w = t_ >> 6, l = t_ & 63, lo4 = l & 15, g = l >> 4;
  const int mh = w >> 2, ch = w & 3;       // 2 x 4 wave grid
  const int srow = t_ >> 2, psl4 = t_ & 3;  // 32B quarter per thread
  const int swk = srow & 15;
  const unsigned char* gA =
      &UT8[((size_t)(b * kN + m0 + srow)) * kN + psl4 * 32];
  const unsigned char* gB =
      &xv8[(((size_t)b * 32 + (psl4 >> 1)) * kC + c0 + srow) * 64 +
           (psl4 & 1) * 32];
  f32x4 acc[4][2] = {};
  ulonglong2 eA[2], eB[2], oA[2], oB[2];
#define LOADSET(RA, RB, T)                                                     \
  {                                                                            \
    RA[0] = *(const ulonglong2*)&gA[(size_t)(T)*128];                          \
    RA[1] = *(const ulonglong2*)&gA[(size_t)(T)*128 + 16];                     \
    RB[0] = *(const ulonglong2*)&gB[(size_t)(T)*65536];                        \
    RB[1] = *(const ulonglong2*)&gB[(size_t)(T)*65536 + 16];                   \
  }
#define STORE_TILE(BUF, RA, RB)                                                \
  {                                                                            \
    _Pragma("unroll") for (int j = 0; j < 4; j++) {                            \
      const int v = (psl4 * 4 + j) ^ swk;                                      \
      const u64 va = (j & 1) ? RA[j >> 1].y : RA[j >> 1].x;                    \
      const u64 vb = (j & 1) ? RB[j >> 1].y : RB[j >> 1].x;                    \
      *(u64*)&As[BUF][srow][v * 8] = va;                                       \
      *(u64*)&Bs[BUF][srow][v * 8] = vb;                                       \
    }                                                                          \
  }
#define FRAGS_MFMA(BUF)                                                        \
  {                                                                            \
    _Pragma("unroll") for (int ks = 0; ks < 4; ks++) {                         \
      long af[4], bfr[2];                                                      \
      _Pragma("unroll") for (int mf = 0; mf < 4; mf++) af[mf] =                \
          *(const long*)&As[BUF][mh * 64 + mf * 16 + lo4]                      \
                            [((ks * 4 + g) ^ lo4) * 8];                        \
      _Pragma("unroll") for (int cf = 0; cf < 2; cf++) bfr[cf] =               \
          *(const long*)&Bs[BUF][ch * 32 + cf * 16 + lo4]                      \
                            [((ks * 4 + g) ^ lo4) * 8];                        \
      _Pragma("unroll") for (int mf = 0; mf < 4; mf++)                         \
          _Pragma("unroll") for (int cf = 0; cf < 2; cf++) acc[mf][cf] =       \
              MFMA8(af[mf], bfr[cf], acc[mf][cf]);                             \
    }                                                                          \
  }
  // prologue: iter0 -> LDS[0]; iter1 pending in regs
  LOADSET(eA, eB, 0);
  STORE_TILE(0, eA, eB);
  LOADSET(oA, oB, 1);
  barrier_lds();
  for (int tt2 = 0; tt2 < 16; tt2 += 2) {
    if (tt2 + 2 < 16) LOADSET(eA, eB, tt2 + 2);
    FRAGS_MFMA(0);
    STORE_TILE(1, oA, oB);
    barrier_lds();
    if (tt2 + 3 < 16) LOADSET(oA, oB, tt2 + 3);
    FRAGS_MFMA(1);
    if (tt2 + 2 < 16) STORE_TILE(0, eA, eB);
    barrier_lds();
  }
#undef FRAGS_MFMA
#undef STORE_TILE
#undef LOADSET
  // epilogue: h = x - 2^-8 * acc; per-wave LDS transpose -> hT[m][c]
  bf16* bncw = ((bf16*)As) + w * 16 * 72;  // 8 waves x 2304B = 18KB <= 32KB
#pragma unroll
  for (int mf = 0; mf < 4; mf++) {
    const int mbase = m0 + mh * 64 + mf * 16;
    float hh[2][4];
#pragma unroll
    for (int cf = 0; cf < 2; cf++) {
      const int c = c0 + ch * 32 + cf * 16 + lo4;
      const f32x4 xval =
          *(const f32x4*)&x[((size_t)(b * kC + c)) * kN + mbase + g * 4];
#pragma unroll
      for (int r = 0; r < 4; r++)
        hh[cf][r] = xval[r] - acc[mf][cf][r] * 0.00390625f;
    }
#pragma unroll
    for (int cf = 0; cf < 2; cf++)
#pragma unroll
      for (int r = 0; r < 4; r++)
        bncw[(4 * g + r) * 72 + cf * 16 + lo4] = (bf16)hh[cf][r];
    {
      const int rr = l >> 2, seg = (l & 3) * 8;
      const bf16x8 v0 = *(const bf16x8*)&bncw[rr * 72 + seg];
      *(bf16x8*)&hT[((size_t)(b * kN + mbase + rr)) * kC + c0 + ch * 32 +
                    seg] = v0;
    }
  }
}

// -------- final: D[n][c] = hT[n][k] wt[c][k]; BN+ReLU+residual
__global__ __launch_bounds__(256, 2) void k_final(
    const bf16* __restrict__ hT, const bf16* __restrict__ wt_bf,
    const float* __restrict__ x, const float* __restrict__ bt,
    const float* __restrict__ beta, const float* __restrict__ rmean,
    const float* __restrict__ invg, float* __restrict__ out) {
  __shared__ __align__(16) bf16 As[2][128][32];
  __shared__ __align__(16) bf16 Bs[2][128][32];
  const int blk = blockIdx.x;  // 512 = 8b x (16nb x 4cb)
  const int b = blk & 7, tile = blk >> 3;
  const int cb = tile & 3, nb = tile >> 2;
  const int n0 = nb * 128, c0 = cb * 128;
  const int t_ = threadIdx.x, w = t_ >> 6, l = t_ & 63, lo4 = l & 15, g = l >> 4;
  const int mh = w >> 1, ch = w & 1;
  const int srow = w * 16 + (l >> 2), sch = l & 3;
  const int spos = sch ^ ((l >> 3) & 3);
  const int rpos = g ^ ((lo4 >> 1) & 3);
  const bf16* gA0 = &hT[((size_t)(b * kN + n0 + srow)) * kC + sch * 8];
  const bf16* gA1 = gA0 + (size_t)64 * kC;
  const bf16* gB0 = &wt_bf[(size_t)(c0 + srow) * kC + sch * 8];
  const bf16* gB1 = gB0 + (size_t)64 * kC;
  f32x4 acc[4][4] = {};
  bf16x8 ra0, ra1, rb0, rb1;
  ra0 = *(const bf16x8*)&gA0[0];
  ra1 = *(const bf16x8*)&gA1[0];
  rb0 = *(const bf16x8*)&gB0[0];
  rb1 = *(const bf16x8*)&gB1[0];
  *(bf16x8*)&As[0][srow][spos * 8] = ra0;
  *(bf16x8*)&As[0][srow + 64][spos * 8] = ra1;
  *(bf16x8*)&Bs[0][srow][spos * 8] = rb0;
  *(bf16x8*)&Bs[0][srow + 64][spos * 8] = rb1;
  __syncthreads();
  for (int tt = 0; tt < 16; tt++) {
    const int buf = tt & 1;
    if (tt < 15) {
      const int k0 = (tt + 1) * 32;
      ra0 = *(const bf16x8*)&gA0[k0];
      ra1 = *(const bf16x8*)&gA1[k0];
      rb0 = *(const bf16x8*)&gB0[k0];
      rb1 = *(const bf16x8*)&gB1[k0];
    }
    bf16x8 af[4], bfr[4];
#pragma unroll
    for (int nf = 0; nf < 4; nf++)
      af[nf] = *(const bf16x8*)&As[buf][mh * 64 + nf * 16 + lo4][rpos * 8];
#pragma unroll
    for (int cf = 0; cf < 4; cf++)
      bfr[cf] = *(const bf16x8*)&Bs[buf][ch * 64 + cf * 16 + lo4][rpos * 8];
#pragma unroll
    for (int nf = 0; nf < 4; nf++)
#pragma unroll
      for (int cf = 0; cf < 4; cf++)
        acc[nf][cf] = MFMA16(af[nf], bfr[cf], acc[nf][cf]);
    if (tt < 15) {
      *(bf16x8*)&As[buf ^ 1][srow][spos * 8] = ra0;
      *(bf16x8*)&As[buf ^ 1][srow + 64][spos * 8] = ra1;
      *(bf16x8*)&Bs[buf ^ 1][srow][spos * 8] = rb0;
      *(bf16x8*)&Bs[buf ^ 1][srow + 64][spos * 8] = rb1;
    }
    __syncthreads();
  }
#pragma unroll
  for (int cf = 0; cf < 4; cf++) {
    const int c = c0 + ch * 64 + cf * 16 + lo4;
    const float btv = bt[c], rmv = rmean[c], igv = invg[c], bev = beta[c];
#pragma unroll
    for (int nf = 0; nf < 4; nf++) {
      const int nbase = n0 + mh * 64 + nf * 16 + g * 4;
      const size_t base = ((size_t)(b * kC + c)) * kN + nbase;
      const f32x4 xval = *(const f32x4*)&x[base];
      f32x4 o;
#pragma unroll
      for (int r = 0; r < 4; r++) {
        float v = (acc[nf][cf][r] + btv - rmv) * igv + bev;
        v = fmaxf(v, 0.0f);
        o[r] = xval[r] + v;
      }
      *(f32x4*)&out[base] = o;
    }
  }
}

extern "C" void kernel_launch(void* const* d_in, const int* in_sizes, int n_in,
                              void* d_out, int out_size, void* d_ws,
                              size_t ws_size, hipStream_t stream) {
  const float* x = (const float*)d_in[0];
  const float* query = (const float*)d_in[1];
  const int* mask = (const int*)d_in[2];
  const float* wqk = (const float*)d_in[3];
  const float* wv = (const float*)d_in[4];
  const float* bv = (const float*)d_in[5];
  const float* wt = (const float*)d_in[6];
  const float* bt = (const float*)d_in[7];
  const float* gamma = (const float*)d_in[8];
  const float* beta = (const float*)d_in[9];
  const float* rmean = (const float*)d_in[10];
  const float* rvar = (const float*)d_in[11];
  float* out = (float*)d_out;
  char* wsb = (char*)d_ws;

  const size_t MB = 1024 * 1024;
  unsigned char* UT8 = (unsigned char*)wsb;      // 32 MB [b][m][n] fp8
  unsigned char* xv8 = (unsigned char*)(wsb + 32 * MB);  // 8 MB fp8 tiled
  bf16* hT = (bf16*)(wsb + 40 * MB);             // 8 MB [b][n][c]
  unsigned char* qT8 = (unsigned char*)(wsb + 48 * MB);  // 2 MB
  unsigned char* kT8 = (unsigned char*)(wsb + 50 * MB);  // 2 MB
  bf16* trbufQ = (bf16*)(wsb + 52 * MB);         // 16 MB
  bf16* trbufX = (bf16*)(wsb + 68 * MB);         // 16 MB
  bf16* wqk_bf = (bf16*)(wsb + 84 * MB);         // 128 KB
  bf16* wv_bf = wqk_bf + 65536;                  // 512 KB
  bf16* wt_bf = wv_bf + 262144;                  // 512 KB
  float* invg = (float*)(wt_bf + 262144);        // 2 KB
  float* Ssum = invg + 512;                      // 64 KB
  float* cnt = Ssum + kB * kN;                   // 32 B

  k_prep<<<136, 256, 0, stream>>>(mask, wqk, wv, wt, gamma, rvar, cnt, wqk_bf,
                                  wv_bf, wt_bf, invg, Ssum);
  k_tr2<<<dim3(kN / 64, kC / 32, 16), 256, 0, stream>>>(query, x, trbufQ,
                                                        trbufX);
  k_projQK<<<dim3(16, kB, 2), 256, 0, stream>>>(trbufQ, trbufX, wqk_bf, qT8,
                                                kT8);
  k_sum<<<512, 256, 0, stream>>>(qT8, kT8, mask, cnt, UT8, Ssum);
  k_projV<<<512, 256, 0, stream>>>(trbufX, wv_bf, bv, Ssum, xv8);
  k_attn2<<<512, 512, 0, stream>>>(UT8, xv8, x, hT);
  k_final<<<512, 256, 0, stream>>>(hT, wt_bf, x, bt, beta, rmean, invg, out);
}

// Round 24
// 128.777 us; speedup vs baseline: 1.0359x; 1.0359x over previous
//
#include <hip/hip_runtime.h>
#include <math.h>

typedef __bf16 bf16;
typedef bf16 bf16x8 __attribute__((ext_vector_type(8)));
typedef bf16 bf16x4 __attribute__((ext_vector_type(4)));
typedef float f32x4 __attribute__((ext_vector_type(4)));
typedef unsigned long long u64;

constexpr int kB = 8, kC = 512, kC4 = 128, kN = 2048;

#define MFMA16(a, b, c) __builtin_amdgcn_mfma_f32_16x16x32_bf16(a, b, c, 0, 0, 0)
#define MFMA8(a, b, c) \
  __builtin_amdgcn_mfma_f32_16x16x32_fp8_fp8(a, b, c, 0, 0, 0)

__device__ __forceinline__ unsigned pack4_fp8(float a, float b, float c,
                                              float d) {
  unsigned v = 0;
  v = __builtin_amdgcn_cvt_pk_fp8_f32(a, b, v, false);
  v = __builtin_amdgcn_cvt_pk_fp8_f32(c, d, v, true);
  return v;
}

// barrier with LDS drain only (no vmcnt drain)
__device__ __forceinline__ void barrier_lds() {
  asm volatile("s_waitcnt lgkmcnt(0)\n\ts_barrier" ::: "memory");
}

// ---------------------------------------------------------------- prep
__global__ __launch_bounds__(256) void k_prep(
    const int* __restrict__ mask, const float* __restrict__ wqk,
    const float* __restrict__ wv, const float* __restrict__ wt,
    const float* __restrict__ gamma, const float* __restrict__ rvar,
    float* __restrict__ cnt, bf16* __restrict__ wqk_bf,
    bf16* __restrict__ wv_bf, bf16* __restrict__ wt_bf,
    float* __restrict__ invg, float* __restrict__ Ssum) {
  const int t = threadIdx.x;
  if (blockIdx.x < 8) {
    const int b = blockIdx.x;
    int s = 0;
    for (int i = t; i < kN; i += 256) s += mask[b * kN + i];
    __shared__ int red[256];
    red[t] = s;
    __syncthreads();
    for (int off = 128; off > 0; off >>= 1) {
      if (t < off) red[t] += red[t + off];
      __syncthreads();
    }
    if (t == 0) cnt[b] = (float)red[0];
    return;
  }
  const int total = 65536 + 262144 + 262144 + 512 + 16384;
  for (int i = (blockIdx.x - 8) * 256 + t; i < total; i += 128 * 256) {
    if (i < 65536) {
      wqk_bf[i] = (bf16)wqk[i];
    } else if (i < 327680) {
      wv_bf[i - 65536] = (bf16)wv[i - 65536];
    } else if (i < 589824) {
      wt_bf[i - 327680] = (bf16)wt[i - 327680];
    } else if (i < 590336) {
      const int j = i - 589824;
      invg[j] = gamma[j] * rsqrtf(rvar[j] + 1e-5f);
    } else {
      Ssum[i - 590336] = 0.0f;
    }
  }
}

// ---------------- transpose+convert both inputs: [C][N] f32 -> [N][C] bf16
__global__ __launch_bounds__(256) void k_tr2(const float* __restrict__ Q,
                                             const float* __restrict__ X,
                                             bf16* __restrict__ XTq,
                                             bf16* __restrict__ XTx) {
  __shared__ float tile[32][69];
  const int z = blockIdx.z, b = z & 7;
  const float* Xs = (z < 8) ? Q : X;
  bf16* XT = (z < 8) ? XTq : XTx;
  const int c0 = blockIdx.y * 32, n0 = blockIdx.x * 64;
  const int t = threadIdx.x;
  const int cc = t >> 4, n4 = (t & 15) * 4;
#pragma unroll
  for (int p = 0; p < 2; p++) {
    const int c = p * 16 + cc;
    const f32x4 v =
        *(const f32x4*)&Xs[((size_t)(b * kC + c0 + c)) * kN + n0 + n4];
    tile[c][n4 + 0] = v[0];
    tile[c][n4 + 1] = v[1];
    tile[c][n4 + 2] = v[2];
    tile[c][n4 + 3] = v[3];
  }
  __syncthreads();
  const int n = t >> 2, c8 = (t & 3) * 8;
  bf16x8 o;
#pragma unroll
  for (int j = 0; j < 8; j++) o[j] = (bf16)tile[c8 + j][n];
  *(bf16x8*)&XT[((size_t)(b * kN + n0 + n)) * kC + c0 + c8] = o;
}

// -------- q/k projections (staged GEMM): OT8[b][n][128] fp8 = (wqk @ src)^T
__global__ __launch_bounds__(256, 2) void k_projQK(
    const bf16* __restrict__ XTq, const bf16* __restrict__ XTx,
    const bf16* __restrict__ W, unsigned char* __restrict__ qT8,
    unsigned char* __restrict__ kT8) {
  __shared__ __align__(16) bf16 As[2][128][32];
  __shared__ __align__(16) bf16 Bs[2][128][32];
  const int nb = blockIdx.x, b = blockIdx.y, src = blockIdx.z;
  const bf16* XT = src ? XTx : XTq;
  unsigned char* OT8 = src ? kT8 : qT8;
  const int n0 = nb * 128;
  const int t_ = threadIdx.x, w = t_ >> 6, l = t_ & 63, lo4 = l & 15, g = l >> 4;
  const int mh = w >> 1, ch = w & 1;
  const int srow = w * 16 + (l >> 2), sch = l & 3;
  const int spos = sch ^ ((l >> 3) & 3);
  const int rpos = g ^ ((lo4 >> 1) & 3);
  const bf16* gA0 = &XT[((size_t)(b * kN + n0 + srow)) * kC + sch * 8];
  const bf16* gA1 = gA0 + (size_t)64 * kC;
  const bf16* gB0 = &W[(size_t)srow * kC + sch * 8];
  const bf16* gB1 = gB0 + (size_t)64 * kC;
  f32x4 acc[4][4] = {};
  bf16x8 ra0, ra1, rb0, rb1;
  ra0 = *(const bf16x8*)&gA0[0];
  ra1 = *(const bf16x8*)&gA1[0];
  rb0 = *(const bf16x8*)&gB0[0];
  rb1 = *(const bf16x8*)&gB1[0];
  *(bf16x8*)&As[0][srow][spos * 8] = ra0;
  *(bf16x8*)&As[0][srow + 64][spos * 8] = ra1;
  *(bf16x8*)&Bs[0][srow][spos * 8] = rb0;
  *(bf16x8*)&Bs[0][srow + 64][spos * 8] = rb1;
  __syncthreads();
  for (int tt = 0; tt < 16; tt++) {
    const int buf = tt & 1;
    if (tt < 15) {
      const int k0 = (tt + 1) * 32;
      ra0 = *(const bf16x8*)&gA0[k0];
      ra1 = *(const bf16x8*)&gA1[k0];
      rb0 = *(const bf16x8*)&gB0[k0];
      rb1 = *(const bf16x8*)&gB1[k0];
    }
    bf16x8 af[4], bfr[4];
#pragma unroll
    for (int nf = 0; nf < 4; nf++)
      af[nf] = *(const bf16x8*)&As[buf][mh * 64 + nf * 16 + lo4][rpos * 8];
#pragma unroll
    for (int cf = 0; cf < 4; cf++)
      bfr[cf] = *(const bf16x8*)&Bs[buf][ch * 64 + cf * 16 + lo4][rpos * 8];
#pragma unroll
    for (int nf = 0; nf < 4; nf++)
#pragma unroll
      for (int cf = 0; cf < 4; cf++)
        acc[nf][cf] = MFMA16(af[nf], bfr[cf], acc[nf][cf]);
    if (tt < 15) {
      *(bf16x8*)&As[buf ^ 1][srow][spos * 8] = ra0;
      *(bf16x8*)&As[buf ^ 1][srow + 64][spos * 8] = ra1;
      *(bf16x8*)&Bs[buf ^ 1][srow][spos * 8] = rb0;
      *(bf16x8*)&Bs[buf ^ 1][srow + 64][spos * 8] = rb1;
    }
    __syncthreads();
  }
  // epilogue: per-wave LDS transpose -> fp8 pack -> OT8[n][d]
  bf16* bncw = ((bf16*)As) + w * 16 * 72;
#pragma unroll
  for (int nf = 0; nf < 4; nf++) {
    const int nbase = n0 + mh * 64 + nf * 16;
#pragma unroll
    for (int cf = 0; cf < 4; cf++)
#pragma unroll
      for (int r = 0; r < 4; r++)
        bncw[(4 * g + r) * 72 + cf * 16 + lo4] = (bf16)acc[nf][cf][r];
    const int rr = l >> 2, seg = (l & 3) * 16;
    const bf16x8 v0 = *(const bf16x8*)&bncw[rr * 72 + seg];
    const bf16x8 v1 = *(const bf16x8*)&bncw[rr * 72 + seg + 8];
    int4 o;
    o.x = (int)pack4_fp8((float)v0[0], (float)v0[1], (float)v0[2],
                         (float)v0[3]);
    o.y = (int)pack4_fp8((float)v0[4], (float)v0[5], (float)v0[6],
                         (float)v0[7]);
    o.z = (int)pack4_fp8((float)v1[0], (float)v1[1], (float)v1[2],
                         (float)v1[3]);
    o.w = (int)pack4_fp8((float)v1[4], (float)v1[5], (float)v1[6],
                         (float)v1[7]);
    *(int4*)&OT8[((size_t)(b * kN + nbase + rr)) * kC4 + ch * 64 + seg] = o;
  }
}

// ---------------- pass 1 (fp8 energy): UT8[m][n] = exp-factor; partial S[n]
__global__ __launch_bounds__(256) void k_sum(
    const unsigned char* __restrict__ qT8, const unsigned char* __restrict__ kT8,
    const int* __restrict__ mask, const float* __restrict__ cnt,
    unsigned char* __restrict__ UT8, float* __restrict__ Ssum) {
  __shared__ __align__(16) unsigned char kts[2][64][128];
  __shared__ __align__(16) unsigned Ubuf[64][16];
  __shared__ int mss[2][64];
  const int blk = blockIdx.x;
  const int b = blk & 7, nb = (blk >> 3) & 31, mh2 = blk >> 8;
  const int m00 = mh2 * 1024;
  const int t_ = threadIdx.x, w = t_ >> 6, l = t_ & 63, lo4 = l & 15, g = l >> 4;
  const float invd = 1.0f / (cnt[b] + 1e-9f);
  const int n0 = nb * 64;
  u64 aq[4];
#pragma unroll
  for (int ks = 0; ks < 4; ks++)
    aq[ks] = *(const u64*)&qT8[((size_t)(b * kN + n0 + w * 16 + lo4)) * kC4 +
                               ks * 32 + g * 8];
  const int nq = n0 + w * 16 + g * 4;
  const int4 mi = *(const int4*)&mask[b * kN + nq];
  const int mn4[4] = {mi.x, mi.y, mi.z, mi.w};
  float rs4[4] = {0.0f, 0.0f, 0.0f, 0.0f};
  const int srow = t_ >> 2, sq = t_ & 3;
  const int swk = srow & 15;
  u64 rg[4];
#pragma unroll
  for (int j = 0; j < 4; j++)
    rg[j] = *(const u64*)&kT8[((size_t)(b * kN + m00 + srow)) * kC4 + sq * 32 +
                              j * 8];
#pragma unroll
  for (int j = 0; j < 4; j++)
    *(u64*)&kts[0][srow][((sq * 4 + j) ^ swk) * 8] = rg[j];
  if (t_ < 16)
    *(int4*)&mss[0][t_ * 4] = *(const int4*)&mask[b * kN + m00 + t_ * 4];
  __syncthreads();
  for (int tt = 0; tt < 16; tt++) {
    const int buf = tt & 1;
    if (tt < 15) {
      const int m0 = m00 + (tt + 1) * 64;
#pragma unroll
      for (int j = 0; j < 4; j++)
        rg[j] = *(const u64*)&kT8[((size_t)(b * kN + m0 + srow)) * kC4 +
                                  sq * 32 + j * 8];
    }
#pragma unroll
    for (int mf = 0; mf < 4; mf++) {
      f32x4 e = {};
#pragma unroll
      for (int ks = 0; ks < 4; ks++) {
        const long bk =
            *(const long*)&kts[buf][mf * 16 + lo4][((ks * 4 + g) ^ lo4) * 8];
        e = MFMA8((long)aq[ks], bk, e);
      }
      const int mmv = mss[buf][mf * 16 + lo4];
      float u[4];
#pragma unroll
      for (int r = 0; r < 4; r++) {
        u[r] = mmv ? (mn4[r] ? __expf(e[r] * invd) : 1.0f) : 0.0f;
        rs4[r] += u[r];
      }
      Ubuf[mf * 16 + lo4][(w * 4 + g) ^ lo4] =
          pack4_fp8(u[0], u[1], u[2], u[3]);
    }
    __syncthreads();
    if (tt < 15) {
#pragma unroll
      for (int j = 0; j < 4; j++)
        *(u64*)&kts[buf ^ 1][srow][((sq * 4 + j) ^ swk) * 8] = rg[j];
      if (t_ < 16)
        *(int4*)&mss[buf ^ 1][t_ * 4] =
            *(const int4*)&mask[b * kN + m00 + (tt + 1) * 64 + t_ * 4];
    }
    {
      const int row = t_ >> 2, q = t_ & 3;
      int4 pkt;
      pkt.x = (int)Ubuf[row][(q * 4 + 0) ^ (row & 15)];
      pkt.y = (int)Ubuf[row][(q * 4 + 1) ^ (row & 15)];
      pkt.z = (int)Ubuf[row][(q * 4 + 2) ^ (row & 15)];
      pkt.w = (int)Ubuf[row][(q * 4 + 3) ^ (row & 15)];
      *(int4*)&UT8[((size_t)(b * kN + m00 + tt * 64 + row)) * kN + n0 +
                   q * 16] = pkt;
    }
    __syncthreads();
  }
#pragma unroll
  for (int r = 0; r < 4; r++) {
#pragma unroll
    for (int off = 1; off < 16; off <<= 1) rs4[r] += __shfl_xor(rs4[r], off);
  }
  if (lo4 == 0) {
#pragma unroll
    for (int r = 0; r < 4; r++) atomicAdd(&Ssum[b * kN + nq + r], rs4[r]);
  }
}

// -------- value projection fused with 256/Ssum scaling -> xv8 fp8 tiled
__global__ __launch_bounds__(256, 2) void k_projV(
    const bf16* __restrict__ XTx, const bf16* __restrict__ Wv,
    const float* __restrict__ bv, const float* __restrict__ Ssum,
    unsigned char* __restrict__ xv8) {
  __shared__ __align__(16) bf16 As[2][128][32];
  __shared__ __align__(16) bf16 Bs[2][128][32];
  const int blk = blockIdx.x;  // 512 = 8b x (16nb x 4cb)
  const int b = blk & 7, tile = blk >> 3;
  const int cb = tile & 3, nb = tile >> 2;
  const int n0 = nb * 128, c0 = cb * 128;
  const int t_ = threadIdx.x, w = t_ >> 6, l = t_ & 63, lo4 = l & 15, g = l >> 4;
  const int mh = w >> 1, ch = w & 1;
  const int srow = w * 16 + (l >> 2), sch = l & 3;
  const int spos = sch ^ ((l >> 3) & 3);
  const int rpos = g ^ ((lo4 >> 1) & 3);
  const bf16* gA0 = &XTx[((size_t)(b * kN + n0 + srow)) * kC + sch * 8];
  const bf16* gA1 = gA0 + (size_t)64 * kC;
  const bf16* gB0 = &Wv[(size_t)(c0 + srow) * kC + sch * 8];
  const bf16* gB1 = gB0 + (size_t)64 * kC;
  f32x4 acc[4][4] = {};
  bf16x8 ra0, ra1, rb0, rb1;
  ra0 = *(const bf16x8*)&gA0[0];
  ra1 = *(const bf16x8*)&gA1[0];
  rb0 = *(const bf16x8*)&gB0[0];
  rb1 = *(const bf16x8*)&gB1[0];
  *(bf16x8*)&As[0][srow][spos * 8] = ra0;
  *(bf16x8*)&As[0][srow + 64][spos * 8] = ra1;
  *(bf16x8*)&Bs[0][srow][spos * 8] = rb0;
  *(bf16x8*)&Bs[0][srow + 64][spos * 8] = rb1;
  __syncthreads();
  for (int tt = 0; tt < 16; tt++) {
    const int buf = tt & 1;
    if (tt < 15) {
      const int k0 = (tt + 1) * 32;
      ra0 = *(const bf16x8*)&gA0[k0];
      ra1 = *(const bf16x8*)&gA1[k0];
      rb0 = *(const bf16x8*)&gB0[k0];
      rb1 = *(const bf16x8*)&gB1[k0];
    }
    bf16x8 af[4], bfr[4];
#pragma unroll
    for (int nf = 0; nf < 4; nf++)
      af[nf] = *(const bf16x8*)&As[buf][mh * 64 + nf * 16 + lo4][rpos * 8];
#pragma unroll
    for (int cf = 0; cf < 4; cf++)
      bfr[cf] = *(const bf16x8*)&Bs[buf][ch * 64 + cf * 16 + lo4][rpos * 8];
#pragma unroll
    for (int nf = 0; nf < 4; nf++)
#pragma unroll
      for (int cf = 0; cf < 4; cf++)
        acc[nf][cf] = MFMA16(af[nf], bfr[cf], acc[nf][cf]);
    if (tt < 15) {
      *(bf16x8*)&As[buf ^ 1][srow][spos * 8] = ra0;
      *(bf16x8*)&As[buf ^ 1][srow + 64][spos * 8] = ra1;
      *(bf16x8*)&Bs[buf ^ 1][srow][spos * 8] = rb0;
      *(bf16x8*)&Bs[buf ^ 1][srow + 64][spos * 8] = rb1;
    }
    __syncthreads();
  }
  // epilogue: (acc + bias) * 256/Ssum[n] -> fp8, tiled layout
#pragma unroll
  for (int nf = 0; nf < 4; nf++) {
    const int nbase = n0 + mh * 64 + nf * 16 + g * 4;
    const f32x4 ssv = *(const f32x4*)&Ssum[b * kN + nbase];
    f32x4 s;
#pragma unroll
    for (int r = 0; r < 4; r++) s[r] = 256.0f / ssv[r];
#pragma unroll
    for (int cf = 0; cf < 4; cf++) {
      const int c = c0 + ch * 64 + cf * 16 + lo4;
      const float bvv = bv[c];
      const unsigned o = pack4_fp8((acc[nf][cf][0] + bvv) * s[0],
                                   (acc[nf][cf][1] + bvv) * s[1],
                                   (acc[nf][cf][2] + bvv) * s[2],
                                   (acc[nf][cf][3] + bvv) * s[3]);
      *(unsigned*)&xv8[(((size_t)b * 32 + (nbase >> 6)) * kC + c) * 64 +
                       (nbase & 63)] = o;
    }
  }
}

// -------- pass 2 (fp8, BK=128): x_r = 2^-8 * sum_n UT8[m][n]*xv8[c][n]
// 512 threads (8 waves = 2mh x 4ch, each 64m x 32c). Epilogue subtracts
// bf16 x^T (coalesced) instead of strided f32 x: -48 MB HBM.
__global__ __launch_bounds__(512, 4) void k_attn2(
    const unsigned char* __restrict__ UT8,
    const unsigned char* __restrict__ xv8, const bf16* __restrict__ XTx,
    bf16* __restrict__ hT) {
  __shared__ __align__(16) unsigned char As[2][128][128];
  __shared__ __align__(16) unsigned char Bs[2][128][128];
  const int blk = blockIdx.x;  // 512 = 8b x (16mb x 4cb)
  const int b = blk & 7, tile = blk >> 3;
  const int cb = tile & 3, mb = tile >> 2;
  const int m0 = mb * 128, c0 = cb * 128;
  const int t_ = threadIdx.x, w = t_ >> 6, l = t_ & 63, lo4 = l & 15, g = l >> 4;
  const int mh = w >> 2, ch = w & 3;        // 2 x 4 wave grid
  const int srow = t_ >> 2, psl4 = t_ & 3;  // 32B quarter per thread
  const int swk = srow & 15;
  const unsigned char* gA =
      &UT8[((size_t)(b * kN + m0 + srow)) * kN + psl4 * 32];
  const unsigned char* gB =
      &xv8[(((size_t)b * 32 + (psl4 >> 1)) * kC + c0 + srow) * 64 +
           (psl4 & 1) * 32];
  f32x4 acc[4][2] = {};
  ulonglong2 eA[2], eB[2], oA[2], oB[2];
#define LOADSET(RA, RB, T)                                                     \
  {                                                                            \
    RA[0] = *(const ulonglong2*)&gA[(size_t)(T)*128];                          \
    RA[1] = *(const ulonglong2*)&gA[(size_t)(T)*128 + 16];                     \
    RB[0] = *(const ulonglong2*)&gB[(size_t)(T)*65536];                        \
    RB[1] = *(const ulonglong2*)&gB[(size_t)(T)*65536 + 16];                   \
  }
#define STORE_TILE(BUF, RA, RB)                                                \
  {                                                                            \
    _Pragma("unroll") for (int j = 0; j < 4; j++) {                            \
      const int v = (psl4 * 4 + j) ^ swk;                                      \
      const u64 va = (j & 1) ? RA[j >> 1].y : RA[j >> 1].x;                    \
      const u64 vb = (j & 1) ? RB[j >> 1].y : RB[j >> 1].x;                    \
      *(u64*)&As[BUF][srow][v * 8] = va;                                       \
      *(u64*)&Bs[BUF][srow][v * 8] = vb;                                       \
    }                                                                          \
  }
#define FRAGS_MFMA(BUF)                                                        \
  {                                                                            \
    _Pragma("unroll") for (int ks = 0; ks < 4; ks++) {                         \
      long af[4], bfr[2];                                                      \
      _Pragma("unroll") for (int mf = 0; mf < 4; mf++) af[mf] =                \
          *(const long*)&As[BUF][mh * 64 + mf * 16 + lo4]                      \
                            [((ks * 4 + g) ^ lo4) * 8];                        \
      _Pragma("unroll") for (int cf = 0; cf < 2; cf++) bfr[cf] =               \
          *(const long*)&Bs[BUF][ch * 32 + cf * 16 + lo4]                      \
                            [((ks * 4 + g) ^ lo4) * 8];                        \
      _Pragma("unroll") for (int mf = 0; mf < 4; mf++)                         \
          _Pragma("unroll") for (int cf = 0; cf < 2; cf++) acc[mf][cf] =       \
              MFMA8(af[mf], bfr[cf], acc[mf][cf]);                             \
    }                                                                          \
  }
  // prologue: iter0 -> LDS[0]; iter1 pending in regs
  LOADSET(eA, eB, 0);
  STORE_TILE(0, eA, eB);
  LOADSET(oA, oB, 1);
  barrier_lds();
  for (int tt2 = 0; tt2 < 16; tt2 += 2) {
    if (tt2 + 2 < 16) LOADSET(eA, eB, tt2 + 2);
    FRAGS_MFMA(0);
    STORE_TILE(1, oA, oB);
    barrier_lds();
    if (tt2 + 3 < 16) LOADSET(oA, oB, tt2 + 3);
    FRAGS_MFMA(1);
    if (tt2 + 2 < 16) STORE_TILE(0, eA, eB);
    barrier_lds();
  }
#undef FRAGS_MFMA
#undef STORE_TILE
#undef LOADSET
  // epilogue: transpose x_r (scaled) via LDS; h = xT - x_r with coalesced
  // bf16 xT read; store hT[m][c]
  bf16* bncw = ((bf16*)As) + w * 16 * 72;  // 8 waves x 2304B
#pragma unroll
  for (int mf = 0; mf < 4; mf++) {
    const int mbase = m0 + mh * 64 + mf * 16;
#pragma unroll
    for (int cf = 0; cf < 2; cf++)
#pragma unroll
      for (int r = 0; r < 4; r++)
        bncw[(4 * g + r) * 72 + cf * 16 + lo4] =
            (bf16)(acc[mf][cf][r] * 0.00390625f);
    {
      const int rr = l >> 2, seg = (l & 3) * 8;
      const bf16x8 xr = *(const bf16x8*)&bncw[rr * 72 + seg];
      const bf16x8 xv = *(const bf16x8*)&XTx[((size_t)(b * kN + mbase + rr)) *
                                                 kC +
                                             c0 + ch * 32 + seg];
      bf16x8 o;
#pragma unroll
      for (int j = 0; j < 8; j++) o[j] = (bf16)((float)xv[j] - (float)xr[j]);
      *(bf16x8*)&hT[((size_t)(b * kN + mbase + rr)) * kC + c0 + ch * 32 +
                    seg] = o;
    }
  }
}

// -------- final: D[n][c] = hT[n][k] wt[c][k]; BN+ReLU+residual
__global__ __launch_bounds__(256, 2) void k_final(
    const bf16* __restrict__ hT, const bf16* __restrict__ wt_bf,
    const float* __restrict__ x, const float* __restrict__ bt,
    const float* __restrict__ beta, const float* __restrict__ rmean,
    const float* __restrict__ invg, float* __restrict__ out) {
  __shared__ __align__(16) bf16 As[2][128][32];
  __shared__ __align__(16) bf16 Bs[2][128][32];
  const int blk = blockIdx.x;  // 512 = 8b x (16nb x 4cb)
  const int b = blk & 7, tile = blk >> 3;
  const int cb = tile & 3, nb = tile >> 2;
  const int n0 = nb * 128, c0 = cb * 128;
  const int t_ = threadIdx.x, w = t_ >> 6, l = t_ & 63, lo4 = l & 15, g = l >> 4;
  const int mh = w >> 1, ch = w & 1;
  const int srow = w * 16 + (l >> 2), sch = l & 3;
  const int spos = sch ^ ((l >> 3) & 3);
  const int rpos = g ^ ((lo4 >> 1) & 3);
  const bf16* gA0 = &hT[((size_t)(b * kN + n0 + srow)) * kC + sch * 8];
  const bf16* gA1 = gA0 + (size_t)64 * kC;
  const bf16* gB0 = &wt_bf[(size_t)(c0 + srow) * kC + sch * 8];
  const bf16* gB1 = gB0 + (size_t)64 * kC;
  f32x4 acc[4][4] = {};
  bf16x8 ra0, ra1, rb0, rb1;
  ra0 = *(const bf16x8*)&gA0[0];
  ra1 = *(const bf16x8*)&gA1[0];
  rb0 = *(const bf16x8*)&gB0[0];
  rb1 = *(const bf16x8*)&gB1[0];
  *(bf16x8*)&As[0][srow][spos * 8] = ra0;
  *(bf16x8*)&As[0][srow + 64][spos * 8] = ra1;
  *(bf16x8*)&Bs[0][srow][spos * 8] = rb0;
  *(bf16x8*)&Bs[0][srow + 64][spos * 8] = rb1;
  __syncthreads();
  for (int tt = 0; tt < 16; tt++) {
    const int buf = tt & 1;
    if (tt < 15) {
      const int k0 = (tt + 1) * 32;
      ra0 = *(const bf16x8*)&gA0[k0];
      ra1 = *(const bf16x8*)&gA1[k0];
      rb0 = *(const bf16x8*)&gB0[k0];
      rb1 = *(const bf16x8*)&gB1[k0];
    }
    bf16x8 af[4], bfr[4];
#pragma unroll
    for (int nf = 0; nf < 4; nf++)
      af[nf] = *(const bf16x8*)&As[buf][mh * 64 + nf * 16 + lo4][rpos * 8];
#pragma unroll
    for (int cf = 0; cf < 4; cf++)
      bfr[cf] = *(const bf16x8*)&Bs[buf][ch * 64 + cf * 16 + lo4][rpos * 8];
#pragma unroll
    for (int nf = 0; nf < 4; nf++)
#pragma unroll
      for (int cf = 0; cf < 4; cf++)
        acc[nf][cf] = MFMA16(af[nf], bfr[cf], acc[nf][cf]);
    if (tt < 15) {
      *(bf16x8*)&As[buf ^ 1][srow][spos * 8] = ra0;
      *(bf16x8*)&As[buf ^ 1][srow + 64][spos * 8] = ra1;
      *(bf16x8*)&Bs[buf ^ 1][srow][spos * 8] = rb0;
      *(bf16x8*)&Bs[buf ^ 1][srow + 64][spos * 8] = rb1;
    }
    __syncthreads();
  }
#pragma unroll
  for (int cf = 0; cf < 4; cf++) {
    const int c = c0 + ch * 64 + cf * 16 + lo4;
    const float btv = bt[c], rmv = rmean[c], igv = invg[c], bev = beta[c];
#pragma unroll
    for (int nf = 0; nf < 4; nf++) {
      const int nbase = n0 + mh * 64 + nf * 16 + g * 4;
      const size_t base = ((size_t)(b * kC + c)) * kN + nbase;
      const f32x4 xval = *(const f32x4*)&x[base];
      f32x4 o;
#pragma unroll
      for (int r = 0; r < 4; r++) {
        float v = (acc[nf][cf][r] + btv - rmv) * igv + bev;
        v = fmaxf(v, 0.0f);
        o[r] = xval[r] + v;
      }
      *(f32x4*)&out[base] = o;
    }
  }
}

extern "C" void kernel_launch(void* const* d_in, const int* in_sizes, int n_in,
                              void* d_out, int out_size, void* d_ws,
                              size_t ws_size, hipStream_t stream) {
  const float* x = (const float*)d_in[0];
  const float* query = (const float*)d_in[1];
  const int* mask = (const int*)d_in[2];
  const float* wqk = (const float*)d_in[3];
  const float* wv = (const float*)d_in[4];
  const float* bv = (const float*)d_in[5];
  const float* wt = (const float*)d_in[6];
  const float* bt = (const float*)d_in[7];
  const float* gamma = (const float*)d_in[8];
  const float* beta = (const float*)d_in[9];
  const float* rmean = (const float*)d_in[10];
  const float* rvar = (const float*)d_in[11];
  float* out = (float*)d_out;
  char* wsb = (char*)d_ws;

  const size_t MB = 1024 * 1024;
  unsigned char* UT8 = (unsigned char*)wsb;      // 32 MB [b][m][n] fp8
  unsigned char* xv8 = (unsigned char*)(wsb + 32 * MB);  // 8 MB fp8 tiled
  bf16* hT = (bf16*)(wsb + 40 * MB);             // 8 MB [b][n][c]
  unsigned char* qT8 = (unsigned char*)(wsb + 48 * MB);  // 2 MB
  unsigned char* kT8 = (unsigned char*)(wsb + 50 * MB);  // 2 MB
  bf16* trbufQ = (bf16*)(wsb + 52 * MB);         // 16 MB
  bf16* trbufX = (bf16*)(wsb + 68 * MB);         // 16 MB
  bf16* wqk_bf = (bf16*)(wsb + 84 * MB);         // 128 KB
  bf16* wv_bf = wqk_bf + 65536;                  // 512 KB
  bf16* wt_bf = wv_bf + 262144;                  // 512 KB
  float* invg = (float*)(wt_bf + 262144);        // 2 KB
  float* Ssum = invg + 512;                      // 64 KB
  float* cnt = Ssum + kB * kN;                   // 32 B

  k_prep<<<136, 256, 0, stream>>>(mask, wqk, wv, wt, gamma, rvar, cnt, wqk_bf,
                                  wv_bf, wt_bf, invg, Ssum);
  k_tr2<<<dim3(kN / 64, kC / 32, 16), 256, 0, stream>>>(query, x, trbufQ,
                                                        trbufX);
  k_projQK<<<dim3(16, kB, 2), 256, 0, stream>>>(trbufQ, trbufX, wqk_bf, qT8,
                                                kT8);
  k_sum<<<512, 256, 0, stream>>>(qT8, kT8, mask, cnt, UT8, Ssum);
  k_projV<<<512, 256, 0, stream>>>(trbufX, wv_bf, bv, Ssum, xv8);
  k_attn2<<<512, 512, 0, stream>>>(UT8, xv8, trbufX, hT);
  k_final<<<512, 256, 0, stream>>>(hT, wt_bf, x, bt, beta, rmean, invg, out);
}